// Round 6
// baseline (2055.644 us; speedup 1.0000x reference)
//
#include <hip/hip_runtime.h>

typedef unsigned short bfraw;
typedef __attribute__((ext_vector_type(8))) short short8;
typedef __attribute__((ext_vector_type(4))) float f32x4;

__device__ __forceinline__ float b2f(bfraw u){ return __uint_as_float(((unsigned int)u)<<16); }
__device__ __forceinline__ bfraw f2b(float f){
  unsigned int u = __float_as_uint(f);
  return (bfraw)((u + 0x7FFFu + ((u>>16)&1u)) >> 16);
}
__device__ __forceinline__ void store_out(float* p, float v){ *p = v; }
__device__ __forceinline__ void store_out(bfraw* p, float v){ *p = f2b(v); }

// ---------------- transpose + convert: out[C][R] = bf16(in[R][C]), in fp32 ------
__global__ __launch_bounds__(1024) void transpose_f32_bf16(const float* __restrict__ in,
                                                           bfraw* __restrict__ out,
                                                           int R, int C) {
  __shared__ bfraw tile[64][65];
  const int tx = threadIdx.x, ty = threadIdx.y;
  const int c0 = blockIdx.x*64, r0 = blockIdx.y*64;
  #pragma unroll
  for (int u = 0; u < 4; ++u)
    tile[ty + u*16][tx] = f2b(in[(size_t)(r0 + ty + u*16)*C + c0 + tx]);
  __syncthreads();
  #pragma unroll
  for (int u = 0; u < 4; ++u)
    out[(size_t)(c0 + ty + u*16)*R + r0 + tx] = tile[tx][ty + u*16];
}

// ---------------- layernorm over D=1024: fp32 in, fp32 params, bf16 out ----------
__global__ __launch_bounds__(256) void ln_kernel(const float* __restrict__ x,
                                                 const float* __restrict__ g,
                                                 const float* __restrict__ b,
                                                 bfraw* __restrict__ out) {
  const int row = blockIdx.x, tid = threadIdx.x;
  const f32x4 v = ((const f32x4*)(x + (size_t)row*1024))[tid];
  float s  = v[0]+v[1]+v[2]+v[3];
  float s2 = v[0]*v[0]+v[1]*v[1]+v[2]*v[2]+v[3]*v[3];
  #pragma unroll
  for (int off = 1; off < 64; off <<= 1) { s += __shfl_xor(s, off); s2 += __shfl_xor(s2, off); }
  __shared__ float red[8];
  const int wv = tid>>6, ln_ = tid&63;
  if (ln_ == 0) { red[wv] = s; red[4+wv] = s2; }
  __syncthreads();
  float a  = red[0]+red[1]+red[2]+red[3];
  float a2 = red[4]+red[5]+red[6]+red[7];
  float mean = a*(1.0f/1024.0f);
  float var  = a2*(1.0f/1024.0f) - mean*mean;
  float inv  = rsqrtf(var + 1e-5f);
  const f32x4 gr = ((const f32x4*)g)[tid];
  const f32x4 br = ((const f32x4*)b)[tid];
  ushort4 o4;
  o4.x = f2b((v[0]-mean)*inv*gr[0] + br[0]);
  o4.y = f2b((v[1]-mean)*inv*gr[1] + br[1]);
  o4.z = f2b((v[2]-mean)*inv*gr[2] + br[2]);
  o4.w = f2b((v[3]-mean)*inv*gr[3] + br[3]);
  ((ushort4*)(out + (size_t)row*1024))[tid] = o4;
}

// ---------------- GEMM: C[M,N] = A[M,K] * Bt[N,K]^T (+epilogue) -------------------
// A,Bt bf16; bias/resid fp32; output OutT (bfraw or float); fp32 accum (MFMA).
// EPI: 0 = none, 1 = +bias +resid, 2 = +bias +exact GELU
template<int EPI, typename OutT>
__global__ __launch_bounds__(256) void gemm_bt(const bfraw* __restrict__ A,
                                               const bfraw* __restrict__ Bt,
                                               const float* __restrict__ bias,
                                               const float* __restrict__ resid,
                                               OutT* __restrict__ C,
                                               int M, int N, int K) {
  __shared__ __align__(16) short As[128*32];
  __shared__ __align__(16) short Bs[128*32];
  const int tid = threadIdx.x;
  const int wave = tid>>6, lane = tid&63;
  const int wm = wave>>1, wn = wave&1;
  const int q = lane>>4, r = lane&15;
  const int bm = blockIdx.x, bn = blockIdx.y;

  const int m0 = tid>>2, c0 = tid&3;
  const bfraw* Ag0 = A  + (size_t)(bm*128      + m0)*K + c0*8;
  const bfraw* Ag1 = A  + (size_t)(bm*128 + 64 + m0)*K + c0*8;
  const bfraw* Bg0 = Bt + (size_t)(bn*128      + m0)*K + c0*8;
  const bfraw* Bg1 = Bt + (size_t)(bn*128 + 64 + m0)*K + c0*8;
  short8* Al0 = (short8*)&As[tid*8];
  short8* Al1 = (short8*)&As[(256+tid)*8];
  short8* Bl0 = (short8*)&Bs[tid*8];
  short8* Bl1 = (short8*)&Bs[(256+tid)*8];

  f32x4 acc[4][4];
  #pragma unroll
  for (int mi = 0; mi < 4; ++mi)
    #pragma unroll
    for (int ni = 0; ni < 4; ++ni)
      acc[mi][ni] = (f32x4){0.f, 0.f, 0.f, 0.f};

  for (int k0 = 0; k0 < K; k0 += 32) {
    short8 ra0 = *(const short8*)(Ag0 + k0);
    short8 ra1 = *(const short8*)(Ag1 + k0);
    short8 rb0 = *(const short8*)(Bg0 + k0);
    short8 rb1 = *(const short8*)(Bg1 + k0);
    __syncthreads();
    *Al0 = ra0; *Al1 = ra1; *Bl0 = rb0; *Bl1 = rb1;
    __syncthreads();
    short8 af[4], bfr[4];
    #pragma unroll
    for (int mi = 0; mi < 4; ++mi)
      af[mi] = *(const short8*)&As[(wm*64 + mi*16 + r)*32 + q*8];
    #pragma unroll
    for (int ni = 0; ni < 4; ++ni)
      bfr[ni] = *(const short8*)&Bs[(wn*64 + ni*16 + r)*32 + q*8];
    #pragma unroll
    for (int mi = 0; mi < 4; ++mi)
      #pragma unroll
      for (int ni = 0; ni < 4; ++ni)
        acc[mi][ni] = __builtin_amdgcn_mfma_f32_16x16x32_bf16(af[mi], bfr[ni], acc[mi][ni], 0, 0, 0);
  }

  // epilogue: D[row=q*4+reg][col=r] per 16x16 fragment (m89 layout, x-validated r3/r4)
  #pragma unroll
  for (int mi = 0; mi < 4; ++mi) {
    #pragma unroll
    for (int ni = 0; ni < 4; ++ni) {
      const int gcol = bn*128 + wn*64 + ni*16 + r;
      float bv = 0.f;
      if constexpr (EPI != 0) bv = bias[gcol];
      #pragma unroll
      for (int rg = 0; rg < 4; ++rg) {
        const int grow = bm*128 + wm*64 + mi*16 + q*4 + rg;
        float val = acc[mi][ni][rg];
        if constexpr (EPI != 0) val += bv;
        if constexpr (EPI == 2) val = 0.5f*val*(1.0f + erff(val*0.70710678118654752f));
        if constexpr (EPI == 1) val += resid[(size_t)grow*N + gcol];
        store_out(&C[(size_t)grow*N + gcol], val);
      }
    }
  }
}

// ---------------- flash attention (causal), T=2048, HD=64, scale=1/8 ----------------
// grid: (T/64, B*H); block 256 = 64 queries x 4 lanes; Q in regs, K/V fp32 in LDS.
__global__ __launch_bounds__(256) void flash_attn(const bfraw* __restrict__ qkv,
                                                  bfraw* __restrict__ o) {
  __shared__ __align__(16) float Ks[64*64];
  __shared__ __align__(16) float Vs[64*64];
  const int tid = threadIdx.x;
  const int i = tid>>2, s = tid&3;
  const int q0 = ((int)gridDim.x - 1 - (int)blockIdx.x)*64;   // heavy blocks first
  const int bb = blockIdx.y>>4, h = blockIdx.y&15;

  const size_t qbase = (size_t)(bb*2048 + q0 + i)*3072 + h*64 + s*16;
  float qreg[16];
  #pragma unroll
  for (int u4 = 0; u4 < 4; ++u4) {
    ushort4 qr = *(const ushort4*)&qkv[qbase + u4*4];
    qreg[u4*4+0] = b2f(qr.x); qreg[u4*4+1] = b2f(qr.y);
    qreg[u4*4+2] = b2f(qr.z); qreg[u4*4+3] = b2f(qr.w);
  }
  float m_i = -1.0e30f, l_i = 0.f;
  float oa[16];
  #pragma unroll
  for (int u = 0; u < 16; ++u) oa[u] = 0.f;
  const int q_g = q0 + i;
  const int ntile = (q0>>6) + 1;

  for (int t = 0; t < ntile; ++t) {
    const int j0 = t*64;
    __syncthreads();
    for (int idx = tid; idx < 1024; idx += 256) {
      const int rr = idx>>4, c4 = (idx&15)<<2;
      const size_t base = (size_t)(bb*2048 + j0 + rr)*3072 + h*64 + c4;
      ushort4 kr = *(const ushort4*)&qkv[base + 1024];
      ushort4 vr = *(const ushort4*)&qkv[base + 2048];
      Ks[rr*64+c4+0] = b2f(kr.x); Ks[rr*64+c4+1] = b2f(kr.y);
      Ks[rr*64+c4+2] = b2f(kr.z); Ks[rr*64+c4+3] = b2f(kr.w);
      Vs[rr*64+c4+0] = b2f(vr.x); Vs[rr*64+c4+1] = b2f(vr.y);
      Vs[rr*64+c4+2] = b2f(vr.z); Vs[rr*64+c4+3] = b2f(vr.w);
    }
    __syncthreads();

    for (int cch = 0; cch < 4; ++cch) {
      float sc[16];
      #pragma unroll
      for (int jj = 0; jj < 16; ++jj) {
        const int j = cch*16 + jj;
        const f32x4* kp = (const f32x4*)&Ks[j*64 + s*16];
        float a0 = 0.f;
        #pragma unroll
        for (int v4 = 0; v4 < 4; ++v4) {
          f32x4 kv = kp[v4];
          a0 += qreg[v4*4+0]*kv[0] + qreg[v4*4+1]*kv[1]
              + qreg[v4*4+2]*kv[2] + qreg[v4*4+3]*kv[3];
        }
        sc[jj] = a0;
      }
      #pragma unroll
      for (int jj = 0; jj < 16; ++jj) {   // full dot = sum of the 4 lane-slices
        sc[jj] += __shfl_xor(sc[jj], 1);
        sc[jj] += __shfl_xor(sc[jj], 2);
      }
      float mloc = -1.0e30f;
      #pragma unroll
      for (int jj = 0; jj < 16; ++jj) {
        const int jg = j0 + cch*16 + jj;
        sc[jj] = (jg <= q_g) ? sc[jj]*0.125f : -1.0e30f;
        mloc = fmaxf(mloc, sc[jj]);
      }
      const float m_new = fmaxf(m_i, mloc);
      const float alpha = __expf(m_i - m_new);
      l_i *= alpha;
      #pragma unroll
      for (int u = 0; u < 16; ++u) oa[u] *= alpha;
      m_i = m_new;
      #pragma unroll
      for (int jj = 0; jj < 16; ++jj) {
        const float p = __expf(sc[jj] - m_new);
        l_i += p;
        const int j = cch*16 + jj;
        const f32x4* vp = (const f32x4*)&Vs[j*64 + s*16];
        #pragma unroll
        for (int v4 = 0; v4 < 4; ++v4) {
          f32x4 vv = vp[v4];
          oa[v4*4+0] += p*vv[0]; oa[v4*4+1] += p*vv[1];
          oa[v4*4+2] += p*vv[2]; oa[v4*4+3] += p*vv[3];
        }
      }
    }
  }

  const float invl = 1.0f/l_i;
  bfraw* orow = o + (size_t)(bb*2048 + q0 + i)*1024 + h*64 + s*16;
  #pragma unroll
  for (int u4 = 0; u4 < 4; ++u4) {
    ushort4 o4;
    o4.x = f2b(oa[u4*4+0]*invl); o4.y = f2b(oa[u4*4+1]*invl);
    o4.z = f2b(oa[u4*4+2]*invl); o4.w = f2b(oa[u4*4+3]*invl);
    *(ushort4*)&orow[u4*4] = o4;
  }
}

// ---------------- host ----------------
extern "C" void kernel_launch(void* const* d_in, const int* in_sizes, int n_in,
                              void* d_out, int out_size, void* d_ws, size_t ws_size,
                              hipStream_t stream) {
  (void)in_sizes; (void)n_in;
  const float* x    = (const float*)d_in[0];
  // d_in[1] = causal mask (int32) -- deterministic tril, handled analytically
  const float* ln1g = (const float*)d_in[2];
  const float* ln1b = (const float*)d_in[3];
  const float* ln2g = (const float*)d_in[4];
  const float* ln2b = (const float*)d_in[5];
  const float* qkvw = (const float*)d_in[6];
  const float* outw = (const float*)d_in[7];
  const float* outb = (const float*)d_in[8];
  const float* fc1w = (const float*)d_in[9];
  const float* fc1b = (const float*)d_in[10];
  const float* fc2w = (const float*)d_in[11];
  const float* fc2b = (const float*)d_in[12];
  float* out = (float*)d_out;   // reference output dtype = float32

  char* ws = (char*)d_ws;
  size_t off = 0;
  auto alloc = [&](size_t bytes) -> void* { void* p = ws + off; off += (bytes + 255) & ~(size_t)255; return p; };
  bfraw* wt_qkv = (bfraw*)alloc(3072ULL*1024*2);   // bf16 [3072][1024]
  bfraw* wt_out = (bfraw*)alloc(1024ULL*1024*2);   // bf16 [1024][1024]
  bfraw* wt_fc1 = (bfraw*)alloc(4096ULL*1024*2);   // bf16 [4096][1024]
  bfraw* wt_fc2 = (bfraw*)alloc(1024ULL*4096*2);   // bf16 [1024][4096]
  bfraw* hbuf   = (bfraw*)alloc(8192ULL*1024*2);   // LN out bf16 (reused for LN2)
  float* x1     = (float*)alloc(8192ULL*1024*4);   // x + attn (fp32)
  char*  big    = (char*) alloc(8192ULL*3072*2 + 8192ULL*1024*2);  // qkv + o; reused as fc1-out
  bfraw* qkv  = (bfraw*)big;
  bfraw* obuf = (bfraw*)(big + 8192ULL*3072*2);
  bfraw* hf   = (bfraw*)big;                       // 8192x4096 bf16 == qkv+o exactly

  if (off > ws_size) {  // distinctive huge-value signature
    (void)hipMemsetAsync(d_out, 0x7F, (size_t)out_size*4, stream);
    return;
  }

  dim3 tb(64, 16);
  transpose_f32_bf16<<<dim3(48, 16), tb, 0, stream>>>(qkvw, wt_qkv, 1024, 3072);
  transpose_f32_bf16<<<dim3(16, 16), tb, 0, stream>>>(outw, wt_out, 1024, 1024);
  transpose_f32_bf16<<<dim3(64, 16), tb, 0, stream>>>(fc1w, wt_fc1, 1024, 4096);
  transpose_f32_bf16<<<dim3(16, 64), tb, 0, stream>>>(fc2w, wt_fc2, 4096, 1024);

  ln_kernel<<<8192, 256, 0, stream>>>(x, ln1g, ln1b, hbuf);
  gemm_bt<0, bfraw><<<dim3(64, 24), 256, 0, stream>>>(hbuf, wt_qkv, nullptr, nullptr, qkv, 8192, 3072, 1024);
  flash_attn<<<dim3(32, 64), 256, 0, stream>>>(qkv, obuf);
  gemm_bt<1, float><<<dim3(64, 8), 256, 0, stream>>>(obuf, wt_out, outb, x, x1, 8192, 1024, 1024);
  ln_kernel<<<8192, 256, 0, stream>>>(x1, ln2g, ln2b, hbuf);
  gemm_bt<2, bfraw><<<dim3(64, 32), 256, 0, stream>>>(hbuf, wt_fc1, fc1b, nullptr, hf, 8192, 4096, 1024);
  gemm_bt<1, float><<<dim3(64, 8), 256, 0, stream>>>(hf, wt_fc2, fc2b, x1, out, 8192, 1024, 4096);
}

// Round 7
// 789.265 us; speedup vs baseline: 2.6045x; 2.6045x over previous
//
#include <hip/hip_runtime.h>

typedef unsigned short bfraw;
typedef __attribute__((ext_vector_type(8))) short short8;
typedef __attribute__((ext_vector_type(4))) float f32x4;

__device__ __forceinline__ float b2f(bfraw u){ return __uint_as_float(((unsigned int)u)<<16); }
__device__ __forceinline__ bfraw f2b(float f){
  unsigned int u = __float_as_uint(f);
  return (bfraw)((u + 0x7FFFu + ((u>>16)&1u)) >> 16);
}
__device__ __forceinline__ void store_out(float* p, float v){ *p = v; }
__device__ __forceinline__ void store_out(bfraw* p, float v){ *p = f2b(v); }

// ---------------- transpose + convert: out[C][R] = bf16(in[R][C]), in fp32 ------
__global__ __launch_bounds__(1024) void transpose_f32_bf16(const float* __restrict__ in,
                                                           bfraw* __restrict__ out,
                                                           int R, int C) {
  __shared__ bfraw tile[64][65];
  const int tx = threadIdx.x, ty = threadIdx.y;
  const int c0 = blockIdx.x*64, r0 = blockIdx.y*64;
  #pragma unroll
  for (int u = 0; u < 4; ++u)
    tile[ty + u*16][tx] = f2b(in[(size_t)(r0 + ty + u*16)*C + c0 + tx]);
  __syncthreads();
  #pragma unroll
  for (int u = 0; u < 4; ++u)
    out[(size_t)(c0 + ty + u*16)*R + r0 + tx] = tile[tx][ty + u*16];
}

// ---------------- layernorm over D=1024: fp32 in, fp32 params, bf16 out ----------
__global__ __launch_bounds__(256) void ln_kernel(const float* __restrict__ x,
                                                 const float* __restrict__ g,
                                                 const float* __restrict__ b,
                                                 bfraw* __restrict__ out) {
  const int row = blockIdx.x, tid = threadIdx.x;
  const f32x4 v = ((const f32x4*)(x + (size_t)row*1024))[tid];
  float s  = v[0]+v[1]+v[2]+v[3];
  float s2 = v[0]*v[0]+v[1]*v[1]+v[2]*v[2]+v[3]*v[3];
  #pragma unroll
  for (int off = 1; off < 64; off <<= 1) { s += __shfl_xor(s, off); s2 += __shfl_xor(s2, off); }
  __shared__ float red[8];
  const int wv = tid>>6, ln_ = tid&63;
  if (ln_ == 0) { red[wv] = s; red[4+wv] = s2; }
  __syncthreads();
  float a  = red[0]+red[1]+red[2]+red[3];
  float a2 = red[4]+red[5]+red[6]+red[7];
  float mean = a*(1.0f/1024.0f);
  float var  = a2*(1.0f/1024.0f) - mean*mean;
  float inv  = rsqrtf(var + 1e-5f);
  const f32x4 gr = ((const f32x4*)g)[tid];
  const f32x4 br = ((const f32x4*)b)[tid];
  ushort4 o4;
  o4.x = f2b((v[0]-mean)*inv*gr[0] + br[0]);
  o4.y = f2b((v[1]-mean)*inv*gr[1] + br[1]);
  o4.z = f2b((v[2]-mean)*inv*gr[2] + br[2]);
  o4.w = f2b((v[3]-mean)*inv*gr[3] + br[3]);
  ((ushort4*)(out + (size_t)row*1024))[tid] = o4;
}

// ---------------- GEMM: C[M,N] = A[M,K] * Bt[N,K]^T (+epilogue) -------------------
// EPI: 0 = none, 1 = +bias +resid, 2 = +bias +exact GELU
template<int EPI, typename OutT>
__global__ __launch_bounds__(256) void gemm_bt(const bfraw* __restrict__ A,
                                               const bfraw* __restrict__ Bt,
                                               const float* __restrict__ bias,
                                               const float* __restrict__ resid,
                                               OutT* __restrict__ C,
                                               int M, int N, int K) {
  __shared__ __align__(16) short As[128*32];
  __shared__ __align__(16) short Bs[128*32];
  const int tid = threadIdx.x;
  const int wave = tid>>6, lane = tid&63;
  const int wm = wave>>1, wn = wave&1;
  const int q = lane>>4, r = lane&15;
  const int bm = blockIdx.x, bn = blockIdx.y;

  const int m0 = tid>>2, c0 = tid&3;
  const bfraw* Ag0 = A  + (size_t)(bm*128      + m0)*K + c0*8;
  const bfraw* Ag1 = A  + (size_t)(bm*128 + 64 + m0)*K + c0*8;
  const bfraw* Bg0 = Bt + (size_t)(bn*128      + m0)*K + c0*8;
  const bfraw* Bg1 = Bt + (size_t)(bn*128 + 64 + m0)*K + c0*8;
  short8* Al0 = (short8*)&As[tid*8];
  short8* Al1 = (short8*)&As[(256+tid)*8];
  short8* Bl0 = (short8*)&Bs[tid*8];
  short8* Bl1 = (short8*)&Bs[(256+tid)*8];

  f32x4 acc[4][4];
  #pragma unroll
  for (int mi = 0; mi < 4; ++mi)
    #pragma unroll
    for (int ni = 0; ni < 4; ++ni)
      acc[mi][ni] = (f32x4){0.f, 0.f, 0.f, 0.f};

  for (int k0 = 0; k0 < K; k0 += 32) {
    short8 ra0 = *(const short8*)(Ag0 + k0);
    short8 ra1 = *(const short8*)(Ag1 + k0);
    short8 rb0 = *(const short8*)(Bg0 + k0);
    short8 rb1 = *(const short8*)(Bg1 + k0);
    __syncthreads();
    *Al0 = ra0; *Al1 = ra1; *Bl0 = rb0; *Bl1 = rb1;
    __syncthreads();
    short8 af[4], bfr[4];
    #pragma unroll
    for (int mi = 0; mi < 4; ++mi)
      af[mi] = *(const short8*)&As[(wm*64 + mi*16 + r)*32 + q*8];
    #pragma unroll
    for (int ni = 0; ni < 4; ++ni)
      bfr[ni] = *(const short8*)&Bs[(wn*64 + ni*16 + r)*32 + q*8];
    #pragma unroll
    for (int mi = 0; mi < 4; ++mi)
      #pragma unroll
      for (int ni = 0; ni < 4; ++ni)
        acc[mi][ni] = __builtin_amdgcn_mfma_f32_16x16x32_bf16(af[mi], bfr[ni], acc[mi][ni], 0, 0, 0);
  }

  #pragma unroll
  for (int mi = 0; mi < 4; ++mi) {
    #pragma unroll
    for (int ni = 0; ni < 4; ++ni) {
      const int gcol = bn*128 + wn*64 + ni*16 + r;
      float bv = 0.f;
      if constexpr (EPI != 0) bv = bias[gcol];
      #pragma unroll
      for (int rg = 0; rg < 4; ++rg) {
        const int grow = bm*128 + wm*64 + mi*16 + q*4 + rg;
        float val = acc[mi][ni][rg];
        if constexpr (EPI != 0) val += bv;
        if constexpr (EPI == 2) val = 0.5f*val*(1.0f + erff(val*0.70710678118654752f));
        if constexpr (EPI == 1) val += resid[(size_t)grow*N + gcol];
        store_out(&C[(size_t)grow*N + gcol], val);
      }
    }
  }
}

// ---------------- MFMA flash attention (causal), T=2048, HD=64, scale=1/8 ---------
// grid (32, 64); block 256 = 4 waves; wave w owns Q rows [q0+w*16, q0+w*16+16).
// K LDS [key][dim], Vt LDS [dim][key], P LDS per-wave [row][key] -- all with XOR
// group swizzle: element (row, k) at row*64 + (((k>>3)^(row>>3 or row&7))&7)*8 + (k&7)
// -> 16B-aligned b128 fragment reads, <=4-way conflicts on scattered b16 writes.
__global__ __launch_bounds__(256) void flash_attn(const bfraw* __restrict__ qkv,
                                                  bfraw* __restrict__ o) {
  __shared__ __align__(16) short Ksh[4096];
  __shared__ __align__(16) short Vts[4096];
  __shared__ __align__(16) short Psh[4096];
  const int tid = threadIdx.x;
  const int w = tid >> 6, lane = tid & 63;
  const int r = lane & 15, qd = lane >> 4;
  const int q0 = ((int)gridDim.x - 1 - (int)blockIdx.x) * 64;  // heavy blocks first
  const int bb = blockIdx.y >> 4, h = blockIdx.y & 15;
  const size_t hb = (size_t)bb * 2048;

  // Q A-fragments: lane holds Q[m=r][k=qd*8+ks*32+j]
  short8 qf[2];
  {
    const bfraw* qrow = qkv + (hb + q0 + w*16 + r) * 3072 + h*64;
    qf[0] = *(const short8*)(qrow + qd*8);
    qf[1] = *(const short8*)(qrow + qd*8 + 32);
  }

  f32x4 oacc[4];
  #pragma unroll
  for (int nt = 0; nt < 4; ++nt) oacc[nt] = (f32x4){0.f,0.f,0.f,0.f};
  float m_i[4] = {-3.0e38f,-3.0e38f,-3.0e38f,-3.0e38f};
  float l_i[4] = {0.f,0.f,0.f,0.f};

  short* Pw = &Psh[w * 1024];
  const int ntile = (q0 >> 6) + 1;

  for (int t = 0; t < ntile; ++t) {
    const int j0 = t * 64;
    __syncthreads();
    // ---- stage K [key][dim] and Vt [dim][key] (both swizzled) ----
    #pragma unroll
    for (int pz = 0; pz < 2; ++pz) {
      const int f   = tid + pz*256;
      const int key = f >> 3, dc = (f & 7) * 8;
      const bfraw* base = qkv + (hb + j0 + key) * 3072 + h*64 + dc;
      short8 kv = *(const short8*)(base + 1024);
      short8 vv = *(const short8*)(base + 2048);
      *(short8*)&Ksh[key*64 + ((((dc>>3) ^ (key>>3)) & 7) << 3)] = kv;
      const int kg = key >> 3, k7 = key & 7, dg = dc >> 3;
      #pragma unroll
      for (int i2 = 0; i2 < 8; ++i2)
        Vts[(dc + i2)*64 + (((kg ^ dg) & 7) << 3) + k7] = vv[i2];
    }
    __syncthreads();

    // ---- S = Q K^T : 4 key-tiles x 2 k-steps ----
    f32x4 s4[4];
    #pragma unroll
    for (int kt = 0; kt < 4; ++kt) {
      f32x4 a = (f32x4){0.f,0.f,0.f,0.f};
      const int key = kt*16 + r, kgk = key >> 3;
      #pragma unroll
      for (int ks = 0; ks < 2; ++ks) {
        short8 bf8 = *(const short8*)&Ksh[key*64 + ((((qd + ks*4) ^ kgk) & 7) << 3)];
        a = __builtin_amdgcn_mfma_f32_16x16x32_bf16(qf[ks], bf8, a, 0, 0, 0);
      }
      s4[kt] = a;
    }
    // ---- scale + causal mask (only diagonal tile partial) ----
    const bool diag = (j0 == q0);
    #pragma unroll
    for (int kt = 0; kt < 4; ++kt)
      #pragma unroll
      for (int rg = 0; rg < 4; ++rg) {
        float v = s4[kt][rg] * 0.125f;
        if (diag && (kt*16 + r > w*16 + qd*4 + rg)) v = -3.0e38f;
        s4[kt][rg] = v;
      }
    // ---- row max across 16 lanes of the qd-group ----
    float alpha[4];
    #pragma unroll
    for (int rg = 0; rg < 4; ++rg) {
      float v = fmaxf(fmaxf(s4[0][rg], s4[1][rg]), fmaxf(s4[2][rg], s4[3][rg]));
      v = fmaxf(v, __shfl_xor(v, 1));
      v = fmaxf(v, __shfl_xor(v, 2));
      v = fmaxf(v, __shfl_xor(v, 4));
      v = fmaxf(v, __shfl_xor(v, 8));
      const float mn = fmaxf(m_i[rg], v);
      alpha[rg] = __expf(m_i[rg] - mn);
      m_i[rg] = mn;
      l_i[rg] *= alpha[rg];
    }
    // ---- P = exp(S - m), write bf16 P to per-wave LDS (swizzled) ----
    float lsum[4] = {0.f,0.f,0.f,0.f};
    #pragma unroll
    for (int kt = 0; kt < 4; ++kt) {
      const int kg2 = kt*2 + (r >> 3), k7b = r & 7;
      #pragma unroll
      for (int rg = 0; rg < 4; ++rg) {
        const float p = __expf(s4[kt][rg] - m_i[rg]);
        lsum[rg] += p;
        const int row = qd*4 + rg;
        Pw[row*64 + (((kg2 ^ (row & 7)) & 7) << 3) + k7b] = (short)f2b(p);
      }
    }
    #pragma unroll
    for (int rg = 0; rg < 4; ++rg) {
      float v = lsum[rg];
      v += __shfl_xor(v, 1); v += __shfl_xor(v, 2);
      v += __shfl_xor(v, 4); v += __shfl_xor(v, 8);
      l_i[rg] += v;
      #pragma unroll
      for (int nt = 0; nt < 4; ++nt) oacc[nt][rg] *= alpha[rg];
    }
    // ---- O += P V : A = P (LDS round-trip), B = Vt ----
    short8 pf[2];
    #pragma unroll
    for (int ks = 0; ks < 2; ++ks)
      pf[ks] = *(const short8*)&Pw[r*64 + ((((qd + ks*4) ^ (r & 7)) & 7) << 3)];
    #pragma unroll
    for (int nt = 0; nt < 4; ++nt) {
      const int d = nt*16 + r, dg = d >> 3;
      #pragma unroll
      for (int ks = 0; ks < 2; ++ks) {
        short8 vf = *(const short8*)&Vts[d*64 + ((((qd + ks*4) ^ dg) & 7) << 3)];
        oacc[nt] = __builtin_amdgcn_mfma_f32_16x16x32_bf16(pf[ks], vf, oacc[nt], 0, 0, 0);
      }
    }
  }

  float invl[4];
  #pragma unroll
  for (int rg = 0; rg < 4; ++rg) invl[rg] = 1.0f / l_i[rg];
  #pragma unroll
  for (int nt = 0; nt < 4; ++nt)
    #pragma unroll
    for (int rg = 0; rg < 4; ++rg)
      o[(hb + q0 + w*16 + qd*4 + rg) * 1024 + h*64 + nt*16 + r] = f2b(oacc[nt][rg] * invl[rg]);
}

// ---------------- host ----------------
extern "C" void kernel_launch(void* const* d_in, const int* in_sizes, int n_in,
                              void* d_out, int out_size, void* d_ws, size_t ws_size,
                              hipStream_t stream) {
  (void)in_sizes; (void)n_in;
  const float* x    = (const float*)d_in[0];
  // d_in[1] = causal mask (int32) -- deterministic tril, handled analytically
  const float* ln1g = (const float*)d_in[2];
  const float* ln1b = (const float*)d_in[3];
  const float* ln2g = (const float*)d_in[4];
  const float* ln2b = (const float*)d_in[5];
  const float* qkvw = (const float*)d_in[6];
  const float* outw = (const float*)d_in[7];
  const float* outb = (const float*)d_in[8];
  const float* fc1w = (const float*)d_in[9];
  const float* fc1b = (const float*)d_in[10];
  const float* fc2w = (const float*)d_in[11];
  const float* fc2b = (const float*)d_in[12];
  float* out = (float*)d_out;   // reference output dtype = float32

  char* ws = (char*)d_ws;
  size_t off = 0;
  auto alloc = [&](size_t bytes) -> void* { void* p = ws + off; off += (bytes + 255) & ~(size_t)255; return p; };
  bfraw* wt_qkv = (bfraw*)alloc(3072ULL*1024*2);
  bfraw* wt_out = (bfraw*)alloc(1024ULL*1024*2);
  bfraw* wt_fc1 = (bfraw*)alloc(4096ULL*1024*2);
  bfraw* wt_fc2 = (bfraw*)alloc(1024ULL*4096*2);
  bfraw* hbuf   = (bfraw*)alloc(8192ULL*1024*2);
  float* x1     = (float*)alloc(8192ULL*1024*4);
  char*  big    = (char*) alloc(8192ULL*3072*2 + 8192ULL*1024*2);
  bfraw* qkv  = (bfraw*)big;
  bfraw* obuf = (bfraw*)(big + 8192ULL*3072*2);
  bfraw* hf   = (bfraw*)big;

  if (off > ws_size) {
    (void)hipMemsetAsync(d_out, 0x7F, (size_t)out_size*4, stream);
    return;
  }

  dim3 tb(64, 16);
  transpose_f32_bf16<<<dim3(48, 16), tb, 0, stream>>>(qkvw, wt_qkv, 1024, 3072);
  transpose_f32_bf16<<<dim3(16, 16), tb, 0, stream>>>(outw, wt_out, 1024, 1024);
  transpose_f32_bf16<<<dim3(64, 16), tb, 0, stream>>>(fc1w, wt_fc1, 1024, 4096);
  transpose_f32_bf16<<<dim3(16, 64), tb, 0, stream>>>(fc2w, wt_fc2, 4096, 1024);

  ln_kernel<<<8192, 256, 0, stream>>>(x, ln1g, ln1b, hbuf);
  gemm_bt<0, bfraw><<<dim3(64, 24), 256, 0, stream>>>(hbuf, wt_qkv, nullptr, nullptr, qkv, 8192, 3072, 1024);
  flash_attn<<<dim3(32, 64), 256, 0, stream>>>(qkv, obuf);
  gemm_bt<1, float><<<dim3(64, 8), 256, 0, stream>>>(obuf, wt_out, outb, x, x1, 8192, 1024, 1024);
  ln_kernel<<<8192, 256, 0, stream>>>(x1, ln2g, ln2b, hbuf);
  gemm_bt<2, bfraw><<<dim3(64, 32), 256, 0, stream>>>(hbuf, wt_fc1, fc1b, nullptr, hf, 8192, 4096, 1024);
  gemm_bt<1, float><<<dim3(64, 8), 256, 0, stream>>>(hf, wt_fc2, fc2b, x1, out, 8192, 1024, 4096);
}

// Round 8
// 630.581 us; speedup vs baseline: 3.2599x; 1.2516x over previous
//
#include <hip/hip_runtime.h>

typedef unsigned short bfraw;
typedef __attribute__((ext_vector_type(8))) short short8;
typedef __attribute__((ext_vector_type(4))) float f32x4;

__device__ __forceinline__ float b2f(bfraw u){ return __uint_as_float(((unsigned int)u)<<16); }
__device__ __forceinline__ bfraw f2b(float f){
  unsigned int u = __float_as_uint(f);
  return (bfraw)((u + 0x7FFFu + ((u>>16)&1u)) >> 16);
}
__device__ __forceinline__ void store_out(float* p, float v){ *p = v; }
__device__ __forceinline__ void store_out(bfraw* p, float v){ *p = f2b(v); }
__device__ __forceinline__ void gload_lds16(const bfraw* g, short* l) {
  __builtin_amdgcn_global_load_lds((const __attribute__((address_space(1))) void*)g,
                                   (__attribute__((address_space(3))) void*)l, 16, 0, 0);
}

// ---------------- transpose + convert: out[C][R] = bf16(in[R][C]), in fp32 ------
__global__ __launch_bounds__(1024) void transpose_f32_bf16(const float* __restrict__ in,
                                                           bfraw* __restrict__ out,
                                                           int R, int C) {
  __shared__ bfraw tile[64][65];
  const int tx = threadIdx.x, ty = threadIdx.y;
  const int c0 = blockIdx.x*64, r0 = blockIdx.y*64;
  #pragma unroll
  for (int u = 0; u < 4; ++u)
    tile[ty + u*16][tx] = f2b(in[(size_t)(r0 + ty + u*16)*C + c0 + tx]);
  __syncthreads();
  #pragma unroll
  for (int u = 0; u < 4; ++u)
    out[(size_t)(c0 + ty + u*16)*R + r0 + tx] = tile[tx][ty + u*16];
}

// ---------------- layernorm over D=1024: fp32 in, fp32 params, bf16 out ----------
__global__ __launch_bounds__(256) void ln_kernel(const float* __restrict__ x,
                                                 const float* __restrict__ g,
                                                 const float* __restrict__ b,
                                                 bfraw* __restrict__ out) {
  const int row = blockIdx.x, tid = threadIdx.x;
  const f32x4 v = ((const f32x4*)(x + (size_t)row*1024))[tid];
  float s  = v[0]+v[1]+v[2]+v[3];
  float s2 = v[0]*v[0]+v[1]*v[1]+v[2]*v[2]+v[3]*v[3];
  #pragma unroll
  for (int off = 1; off < 64; off <<= 1) { s += __shfl_xor(s, off); s2 += __shfl_xor(s2, off); }
  __shared__ float red[8];
  const int wv = tid>>6, ln_ = tid&63;
  if (ln_ == 0) { red[wv] = s; red[4+wv] = s2; }
  __syncthreads();
  float a  = red[0]+red[1]+red[2]+red[3];
  float a2 = red[4]+red[5]+red[6]+red[7];
  float mean = a*(1.0f/1024.0f);
  float var  = a2*(1.0f/1024.0f) - mean*mean;
  float inv  = rsqrtf(var + 1e-5f);
  const f32x4 gr = ((const f32x4*)g)[tid];
  const f32x4 br = ((const f32x4*)b)[tid];
  ushort4 o4;
  o4.x = f2b((v[0]-mean)*inv*gr[0] + br[0]);
  o4.y = f2b((v[1]-mean)*inv*gr[1] + br[1]);
  o4.z = f2b((v[2]-mean)*inv*gr[2] + br[2]);
  o4.w = f2b((v[3]-mean)*inv*gr[3] + br[3]);
  ((ushort4*)(out + (size_t)row*1024))[tid] = o4;
}

// ---------------- GEMM: C[M,N] = A[M,K] * Bt[N,K]^T (+epilogue) -------------------
// m97 structure: global_load_lds width=16 staging (async, no VGPR round-trip).
// EPI: 0 = none, 1 = +bias +resid, 2 = +bias +exact GELU
template<int EPI, typename OutT>
__global__ __launch_bounds__(256) void gemm_bt(const bfraw* __restrict__ A,
                                               const bfraw* __restrict__ Bt,
                                               const float* __restrict__ bias,
                                               const float* __restrict__ resid,
                                               OutT* __restrict__ C,
                                               int M, int N, int K) {
  __shared__ __align__(16) short As[128*32];
  __shared__ __align__(16) short Bs[128*32];
  const int tid = threadIdx.x;
  const int wave = tid>>6, lane = tid&63;
  const int wm = wave>>1, wn = wave&1;
  const int q = lane>>4, r = lane&15;
  const int bm = blockIdx.x, bn = blockIdx.y;

  // staging: tile 128 rows x 32 bf16 = 512 x 16B chunks; thread covers f=tid, f=256+tid.
  // LDS addr f*16B = wave-uniform base + lane*16 (global_load_lds constraint m104/m108).
  const int m0 = tid>>2, c0 = tid&3;
  const bfraw* Ag0 = A  + (size_t)(bm*128      + m0)*K + c0*8;
  const bfraw* Ag1 = A  + (size_t)(bm*128 + 64 + m0)*K + c0*8;
  const bfraw* Bg0 = Bt + (size_t)(bn*128      + m0)*K + c0*8;
  const bfraw* Bg1 = Bt + (size_t)(bn*128 + 64 + m0)*K + c0*8;
  short* Al0 = &As[tid*8];
  short* Al1 = &As[(256+tid)*8];
  short* Bl0 = &Bs[tid*8];
  short* Bl1 = &Bs[(256+tid)*8];

  f32x4 acc[4][4];
  #pragma unroll
  for (int mi = 0; mi < 4; ++mi)
    #pragma unroll
    for (int ni = 0; ni < 4; ++ni)
      acc[mi][ni] = (f32x4){0.f, 0.f, 0.f, 0.f};

  for (int k0 = 0; k0 < K; k0 += 32) {
    __syncthreads();               // protect LDS readers of previous tile
    gload_lds16(Ag0 + k0, Al0);
    gload_lds16(Ag1 + k0, Al1);
    gload_lds16(Bg0 + k0, Bl0);
    gload_lds16(Bg1 + k0, Bl1);
    __syncthreads();               // vmcnt drained by compiler before barrier
    short8 af[4], bfr[4];
    #pragma unroll
    for (int mi = 0; mi < 4; ++mi)
      af[mi] = *(const short8*)&As[(wm*64 + mi*16 + r)*32 + q*8];
    #pragma unroll
    for (int ni = 0; ni < 4; ++ni)
      bfr[ni] = *(const short8*)&Bs[(wn*64 + ni*16 + r)*32 + q*8];
    #pragma unroll
    for (int mi = 0; mi < 4; ++mi)
      #pragma unroll
      for (int ni = 0; ni < 4; ++ni)
        acc[mi][ni] = __builtin_amdgcn_mfma_f32_16x16x32_bf16(af[mi], bfr[ni], acc[mi][ni], 0, 0, 0);
  }

  #pragma unroll
  for (int mi = 0; mi < 4; ++mi) {
    #pragma unroll
    for (int ni = 0; ni < 4; ++ni) {
      const int gcol = bn*128 + wn*64 + ni*16 + r;
      float bv = 0.f;
      if constexpr (EPI != 0) bv = bias[gcol];
      #pragma unroll
      for (int rg = 0; rg < 4; ++rg) {
        const int grow = bm*128 + wm*64 + mi*16 + q*4 + rg;
        float val = acc[mi][ni][rg];
        if constexpr (EPI != 0) val += bv;
        if constexpr (EPI == 2) val = 0.5f*val*(1.0f + erff(val*0.70710678118654752f));
        if constexpr (EPI == 1) val += resid[(size_t)grow*N + gcol];
        store_out(&C[(size_t)grow*N + gcol], val);
      }
    }
  }
}

// ---------------- MFMA flash attention (causal), T=2048, HD=64, scale=1/8 ---------
// grid (16, 64): block bx handles q-tiles bx and 31-bx (diagonal pairing -> uniform
// 33 tile-units/block, 1024 co-resident blocks). Register prefetch of next K/V tile
// overlaps global latency with compute. LDS layouts as round 7 (XOR swizzle).
__global__ __launch_bounds__(256) void flash_attn(const bfraw* __restrict__ qkv,
                                                  bfraw* __restrict__ o) {
  __shared__ __align__(16) short Ksh[4096];
  __shared__ __align__(16) short Vts[4096];
  __shared__ __align__(16) short Psh[4096];
  const int tid = threadIdx.x;
  const int w = tid >> 6, lane = tid & 63;
  const int r = lane & 15, qd = lane >> 4;
  const int bb = blockIdx.y >> 4, h = blockIdx.y & 15;
  const size_t hb = (size_t)bb * 2048;
  short* Pw = &Psh[w * 1024];
  const int f0 = tid, f1 = tid + 256;
  const int key0 = f0 >> 3, dc0 = (f0 & 7) * 8;
  const int key1 = f1 >> 3, dc1 = (f1 & 7) * 8;

  for (int pass = 0; pass < 2; ++pass) {
    const int qt = pass ? (31 - (int)blockIdx.x) : (int)blockIdx.x;
    const int q0 = qt * 64;
    const int ntile = qt + 1;

    // Q A-fragments: lane holds Q[m=r][k=qd*8+ks*32+j]
    short8 qf[2];
    {
      const bfraw* qrow = qkv + (hb + q0 + w*16 + r) * 3072 + h*64;
      qf[0] = *(const short8*)(qrow + qd*8);
      qf[1] = *(const short8*)(qrow + qd*8 + 32);
    }

    f32x4 oacc[4];
    #pragma unroll
    for (int nt = 0; nt < 4; ++nt) oacc[nt] = (f32x4){0.f,0.f,0.f,0.f};
    float m_i[4] = {-3.0e38f,-3.0e38f,-3.0e38f,-3.0e38f};
    float l_i[4] = {0.f,0.f,0.f,0.f};

    // prefetch tile 0
    short8 kpre[2], vpre[2];
    {
      const bfraw* b0 = qkv + (hb + key0) * 3072 + h*64 + dc0;
      const bfraw* b1 = qkv + (hb + key1) * 3072 + h*64 + dc1;
      kpre[0] = *(const short8*)(b0 + 1024); vpre[0] = *(const short8*)(b0 + 2048);
      kpre[1] = *(const short8*)(b1 + 1024); vpre[1] = *(const short8*)(b1 + 2048);
    }

    for (int t = 0; t < ntile; ++t) {
      __syncthreads();   // protect LDS vs previous tile / previous pass
      // ---- write prefetched K [key][dim] and Vt [dim][key] (swizzled) ----
      #pragma unroll
      for (int pz = 0; pz < 2; ++pz) {
        const int key = pz ? key1 : key0, dc = pz ? dc1 : dc0;
        *(short8*)&Ksh[key*64 + ((((dc>>3) ^ (key>>3)) & 7) << 3)] = kpre[pz];
        const int kg = key >> 3, k7 = key & 7, dg = dc >> 3;
        #pragma unroll
        for (int i2 = 0; i2 < 8; ++i2)
          Vts[(dc + i2)*64 + (((kg ^ dg) & 7) << 3) + k7] = vpre[pz][i2];
      }
      __syncthreads();
      // ---- prefetch next tile into regs (overlaps compute below) ----
      if (t + 1 < ntile) {
        const int j0n = (t + 1) * 64;
        const bfraw* b0 = qkv + (hb + j0n + key0) * 3072 + h*64 + dc0;
        const bfraw* b1 = qkv + (hb + j0n + key1) * 3072 + h*64 + dc1;
        kpre[0] = *(const short8*)(b0 + 1024); vpre[0] = *(const short8*)(b0 + 2048);
        kpre[1] = *(const short8*)(b1 + 1024); vpre[1] = *(const short8*)(b1 + 2048);
      }

      // ---- S = Q K^T : 4 key-tiles x 2 k-steps ----
      f32x4 s4[4];
      #pragma unroll
      for (int kt = 0; kt < 4; ++kt) {
        f32x4 a = (f32x4){0.f,0.f,0.f,0.f};
        const int key = kt*16 + r, kgk = key >> 3;
        #pragma unroll
        for (int ks = 0; ks < 2; ++ks) {
          short8 bf8 = *(const short8*)&Ksh[key*64 + ((((qd + ks*4) ^ kgk) & 7) << 3)];
          a = __builtin_amdgcn_mfma_f32_16x16x32_bf16(qf[ks], bf8, a, 0, 0, 0);
        }
        s4[kt] = a;
      }
      // ---- scale + causal mask (diagonal tile only) ----
      const bool diag = (t == qt);
      #pragma unroll
      for (int kt = 0; kt < 4; ++kt)
        #pragma unroll
        for (int rg = 0; rg < 4; ++rg) {
          float v = s4[kt][rg] * 0.125f;
          if (diag && (kt*16 + r > w*16 + qd*4 + rg)) v = -3.0e38f;
          s4[kt][rg] = v;
        }
      // ---- online softmax ----
      float alpha[4];
      #pragma unroll
      for (int rg = 0; rg < 4; ++rg) {
        float v = fmaxf(fmaxf(s4[0][rg], s4[1][rg]), fmaxf(s4[2][rg], s4[3][rg]));
        v = fmaxf(v, __shfl_xor(v, 1));
        v = fmaxf(v, __shfl_xor(v, 2));
        v = fmaxf(v, __shfl_xor(v, 4));
        v = fmaxf(v, __shfl_xor(v, 8));
        const float mn = fmaxf(m_i[rg], v);
        alpha[rg] = __expf(m_i[rg] - mn);
        m_i[rg] = mn;
        l_i[rg] *= alpha[rg];
      }
      float lsum[4] = {0.f,0.f,0.f,0.f};
      #pragma unroll
      for (int kt = 0; kt < 4; ++kt) {
        const int kg2 = kt*2 + (r >> 3), k7b = r & 7;
        #pragma unroll
        for (int rg = 0; rg < 4; ++rg) {
          const float p = __expf(s4[kt][rg] - m_i[rg]);
          lsum[rg] += p;
          const int row = qd*4 + rg;
          Pw[row*64 + (((kg2 ^ (row & 7)) & 7) << 3) + k7b] = (short)f2b(p);
        }
      }
      #pragma unroll
      for (int rg = 0; rg < 4; ++rg) {
        float v = lsum[rg];
        v += __shfl_xor(v, 1); v += __shfl_xor(v, 2);
        v += __shfl_xor(v, 4); v += __shfl_xor(v, 8);
        l_i[rg] += v;
        #pragma unroll
        for (int nt = 0; nt < 4; ++nt) oacc[nt][rg] *= alpha[rg];
      }
      // ---- O += P V (P via per-wave LDS round-trip; B = Vt) ----
      short8 pf[2];
      #pragma unroll
      for (int ks = 0; ks < 2; ++ks)
        pf[ks] = *(const short8*)&Pw[r*64 + ((((qd + ks*4) ^ (r & 7)) & 7) << 3)];
      #pragma unroll
      for (int nt = 0; nt < 4; ++nt) {
        const int d = nt*16 + r, dg = d >> 3;
        #pragma unroll
        for (int ks = 0; ks < 2; ++ks) {
          short8 vf = *(const short8*)&Vts[d*64 + ((((qd + ks*4) ^ dg) & 7) << 3)];
          oacc[nt] = __builtin_amdgcn_mfma_f32_16x16x32_bf16(pf[ks], vf, oacc[nt], 0, 0, 0);
        }
      }
    }

    float invl[4];
    #pragma unroll
    for (int rg = 0; rg < 4; ++rg) invl[rg] = 1.0f / l_i[rg];
    #pragma unroll
    for (int nt = 0; nt < 4; ++nt)
      #pragma unroll
      for (int rg = 0; rg < 4; ++rg)
        o[(hb + q0 + w*16 + qd*4 + rg) * 1024 + h*64 + nt*16 + r] = f2b(oacc[nt][rg] * invl[rg]);
  }
}

// ---------------- host ----------------
extern "C" void kernel_launch(void* const* d_in, const int* in_sizes, int n_in,
                              void* d_out, int out_size, void* d_ws, size_t ws_size,
                              hipStream_t stream) {
  (void)in_sizes; (void)n_in;
  const float* x    = (const float*)d_in[0];
  // d_in[1] = causal mask (int32) -- deterministic tril, handled analytically
  const float* ln1g = (const float*)d_in[2];
  const float* ln1b = (const float*)d_in[3];
  const float* ln2g = (const float*)d_in[4];
  const float* ln2b = (const float*)d_in[5];
  const float* qkvw = (const float*)d_in[6];
  const float* outw = (const float*)d_in[7];
  const float* outb = (const float*)d_in[8];
  const float* fc1w = (const float*)d_in[9];
  const float* fc1b = (const float*)d_in[10];
  const float* fc2w = (const float*)d_in[11];
  const float* fc2b = (const float*)d_in[12];
  float* out = (float*)d_out;   // reference output dtype = float32

  char* ws = (char*)d_ws;
  size_t off = 0;
  auto alloc = [&](size_t bytes) -> void* { void* p = ws + off; off += (bytes + 255) & ~(size_t)255; return p; };
  bfraw* wt_qkv = (bfraw*)alloc(3072ULL*1024*2);
  bfraw* wt_out = (bfraw*)alloc(1024ULL*1024*2);
  bfraw* wt_fc1 = (bfraw*)alloc(4096ULL*1024*2);
  bfraw* wt_fc2 = (bfraw*)alloc(1024ULL*4096*2);
  bfraw* hbuf   = (bfraw*)alloc(8192ULL*1024*2);
  float* x1     = (float*)alloc(8192ULL*1024*4);
  char*  big    = (char*) alloc(8192ULL*3072*2 + 8192ULL*1024*2);
  bfraw* qkv  = (bfraw*)big;
  bfraw* obuf = (bfraw*)(big + 8192ULL*3072*2);
  bfraw* hf   = (bfraw*)big;

  if (off > ws_size) {
    (void)hipMemsetAsync(d_out, 0x7F, (size_t)out_size*4, stream);
    return;
  }

  dim3 tb(64, 16);
  transpose_f32_bf16<<<dim3(48, 16), tb, 0, stream>>>(qkvw, wt_qkv, 1024, 3072);
  transpose_f32_bf16<<<dim3(16, 16), tb, 0, stream>>>(outw, wt_out, 1024, 1024);
  transpose_f32_bf16<<<dim3(64, 16), tb, 0, stream>>>(fc1w, wt_fc1, 1024, 4096);
  transpose_f32_bf16<<<dim3(16, 64), tb, 0, stream>>>(fc2w, wt_fc2, 4096, 1024);

  ln_kernel<<<8192, 256, 0, stream>>>(x, ln1g, ln1b, hbuf);
  gemm_bt<0, bfraw><<<dim3(64, 24), 256, 0, stream>>>(hbuf, wt_qkv, nullptr, nullptr, qkv, 8192, 3072, 1024);
  flash_attn<<<dim3(16, 64), 256, 0, stream>>>(qkv, obuf);
  gemm_bt<1, float><<<dim3(64, 8), 256, 0, stream>>>(obuf, wt_out, outb, x, x1, 8192, 1024, 1024);
  ln_kernel<<<8192, 256, 0, stream>>>(x1, ln2g, ln2b, hbuf);
  gemm_bt<2, bfraw><<<dim3(64, 32), 256, 0, stream>>>(hbuf, wt_fc1, fc1b, nullptr, hf, 8192, 4096, 1024);
  gemm_bt<1, float><<<dim3(64, 8), 256, 0, stream>>>(hf, wt_fc2, fc2b, x1, out, 8192, 1024, 4096);
}